// Round 9
// baseline (163.118 us; speedup 1.0000x reference)
//
#include <hip/hip_runtime.h>
#include <hip/hip_fp16.h>
#include <math.h>
#include <stdint.h>

#define NBATCH 2
#define KBOX   512
#define NBOX   (NBATCH*KBOX)
#define CCH    256
#define NBIN   49                 // 7x7 bins
#define NCH    4                  // channels per block = waves per block
#define BPB    (CCH/NCH)          // 64 blocks per box
#define COUT   (CCH*NBIN)         // 12544 outputs per box
#define WCAP   1800               // floats per channel window; proven max idx 1788 (+sentinel)
#define HDRN   8                  // ints per box header
#define TAPN   (12*NBIN)          // 588 packed dwords per box

typedef const uint32_t __attribute__((address_space(1)))* gas_u32p;
typedef uint32_t       __attribute__((address_space(3)))* las_u32p;

// ---------------- kernel 1: per-box header + packed tap table ----------------
__global__ __launch_bounds__(64) void box_prep_kernel(
    const float* __restrict__ boxes, int* __restrict__ hdr, uint32_t* __restrict__ taps)
{
    const int m    = blockIdx.x;
    const int lane = threadIdx.x;

    const float x1 = boxes[m*4+0];
    const float y1 = boxes[m*4+1];
    const float x2 = boxes[m*4+2];
    const float y2 = boxes[m*4+3];

    const float area = (x2 - x1) * (y2 - y1);
    const float size = sqrtf(area);
    float lvlf = floorf(4.0f + log2f(size / 224.0f + 1e-8f));
    lvlf = fminf(fmaxf(lvlf, 2.0f), 5.0f);
    const int lvl = (int)lvlf - 2;    // 0..3

    const int   H     = 256 >> lvl;
    const float scale = 0.25f / (float)(1 << lvl);
    const float Hf    = (float)H;

    const float bx1 = x1 * scale - 0.5f;
    const float by1 = y1 * scale - 0.5f;
    const float bin_w = (x2 * scale - 0.5f - bx1) / 7.0f;
    const float bin_h = (y2 * scale - 0.5f - by1) / 7.0f;

    // window bounds (same clamp math as taps -> taps provably inside)
    const float sx_min = bx1 + 0.25f * bin_w;
    const float sx_max = bx1 + 6.75f * bin_w;
    const float sy_min = by1 + 0.25f * bin_h;
    const float sy_max = by1 + 6.75f * bin_h;
    const int wx0 = min((int)floorf(fmaxf(sx_min, 0.0f)), H - 1);
    const int wy0 = min((int)floorf(fmaxf(sy_min, 0.0f)), H - 1);
    const int wx1 = min(min((int)floorf(fmaxf(sx_max, 0.0f)), H - 1) + 1, H - 1);
    const int wy1 = min(min((int)floorf(fmaxf(sy_max, 0.0f)), H - 1) + 1, H - 1);
    const int hspan = wy1 - wy0 + 1;

    // quad-aligned window: rows start at 16B boundary, length multiple of 4.
    // H is a multiple of 4 and wx1 <= H-1, so quads never cross a row end.
    const int wx0a = wx0 & ~3;
    const int wsp4 = ((wx1 - wx0a + 4) >> 2) << 2;   // align4(wx1-wx0a+1)
    const int qpr  = wsp4 >> 2;                      // quads per row
    const int nq   = hspan * qpr;                    // quads per channel window

    if (lane < NBIN) {
        const int py = lane / 7;
        const int px = lane - py * 7;
        const uint32_t base = (uint32_t)m * TAPN;
        __half2* th = (__half2*)taps;

        #pragma unroll
        for (int s = 0; s < 4; ++s) {
            const int iy = s >> 1;
            const int ix = s & 1;
            const float gy = ((float)(2*py + iy) + 0.5f) * 0.5f;
            const float gx = ((float)(2*px + ix) + 0.5f) * 0.5f;
            const float yy = by1 + gy * bin_h;
            const float xx = bx1 + gx * bin_w;

            const bool valid = (yy >= -1.0f) && (yy <= Hf) && (xx >= -1.0f) && (xx <= Hf);

            const float yc = fmaxf(yy, 0.0f);
            const float xc = fmaxf(xx, 0.0f);
            int yl = min((int)floorf(yc), H - 1);
            int xl = min((int)floorf(xc), H - 1);
            const int yh = min(yl + 1, H - 1);
            const int xh = min(xl + 1, H - 1);
            const float fy = yc - (float)yl;
            float fx = xc - (float)xl;
            if (xh == xl) fx = 0.0f;   // clamped x-pair: hi weight 0 (exact)

            const float vm  = valid ? 0.25f : 0.0f;   // fold 2x2 mean into weights
            const float wyl = (1.0f - fy) * vm;
            const float wyh = fy * vm;

            const int xr  = xl - wx0a;
            const uint32_t olo = (uint32_t)((yl - wy0) * wsp4 + xr);
            const uint32_t ohi = (uint32_t)((yh - wy0) * wsp4 + xr);

            taps[base + s*NBIN + lane] = olo | (ohi << 16);
            th  [base + (4+s)*NBIN + lane] = __floats2half2_rn(wyl*(1.0f-fx), wyh*(1.0f-fx));
            th  [base + (8+s)*NBIN + lane] = __floats2half2_rn(wyl*fx,        wyh*fx);
        }
    }

    if (lane == 0) {
        int* h = hdr + m * HDRN;
        h[0] = lvl;
        h[1] = H;
        h[2] = H * H;
        h[3] = wy0 * H + wx0a;
        h[4] = qpr;
        h[5] = nq;
        h[6] = __float_as_int(1.0f / (float)qpr);
        h[7] = nq << 2;            // sentinel index
    }
}

// -------- kernel 2: per-wave channel, 16B staging, packed taps, no barrier --------
__global__ __launch_bounds__(256, 5) void roi_align_kernel(
    const float* __restrict__ f2, const float* __restrict__ f3,
    const float* __restrict__ f4, const float* __restrict__ f5,
    const int* __restrict__ hdr, const uint32_t* __restrict__ taps,
    float* __restrict__ out)
{
    const int bid  = blockIdx.x;
    // same-box blocks share an XCD (round-robin dispatch): box = low3|hi7
    const int cg   = (bid >> 3) & 63;
    const int m    = (bid & 7) | ((bid >> 9) << 3);
    const int tid  = threadIdx.x;
    const int lane = tid & 63;
    const int wid  = tid >> 6;
    const int b    = m >> 9;          // batch (KBOX == 512)

    __shared__ float win[NCH * WCAP];

    const int* h = hdr + m * HDRN;
    const int   lvl  = h[0];
    const int   H    = h[1];
    const int   HH   = h[2];
    const int   woff = h[3];
    const int   qpr  = h[4];
    const int   nq   = h[5];
    const float rq   = __int_as_float(h[6]);
    const int   nq4  = h[7];

    const float* fptr = (lvl == 0) ? f2 : (lvl == 1) ? f3 : (lvl == 2) ? f4 : f5;
    const int c = cg * NCH + wid;     // this wave's channel
    const float* src0 = fptr + ((size_t)(b * CCH + c)) * HH + woff;
    float* wbase = win + wid * WCAP;  // this wave's private LDS segment

    // ---- stage own window: 16B quads, HBM -> LDS direct ----
    for (int iq = lane; iq < nq; iq += 64) {
        const int r  = (int)(((float)iq + 0.5f) * rq);   // exact for iq < 2048
        const int c4 = (iq - r * qpr) << 2;
        __builtin_amdgcn_global_load_lds(
            (gas_u32p)(const void*)(src0 + r * H + c4),
            (las_u32p)(void*)(&wbase[(iq & ~63) << 2]),
            16, 0, 0);
    }
    // sentinel: the single one-past-end slot a clamped pair-read touches (weight 0)
    if (lane == 0) wbase[nq4] = 0.0f;

    // ---- packed taps: 12 coalesced dword loads (L2/XCD-resident) ----
    const int l = (lane < NBIN) ? lane : NBIN - 1;
    const uint32_t* tb = taps + (uint32_t)m * TAPN;
    const __half2*  th = (const __half2*)tb;

    uint32_t po[4];
    __half2  wl[4], wh[4];
    #pragma unroll
    for (int s = 0; s < 4; ++s) po[s] = tb[s*NBIN + l];
    #pragma unroll
    for (int s = 0; s < 4; ++s) wl[s] = th[(4+s)*NBIN + l];
    #pragma unroll
    for (int s = 0; s < 4; ++s) wh[s] = th[(8+s)*NBIN + l];

    // wave-local drain of own staging + tap loads; fence the scheduler (rule #18)
    asm volatile("s_waitcnt vmcnt(0) lgkmcnt(0)" ::: "memory");
    __builtin_amdgcn_sched_barrier(0);

    // ---- compute: 16 LDS reads + 16 FMAs + 1 store ----
    float acc = 0.0f;
    #pragma unroll
    for (int s = 0; s < 4; ++s) {
        const int olo = (int)(po[s] & 0xffffu);
        const int ohi = (int)(po[s] >> 16);
        const float2 a  = __half22float2(wl[s]);
        const float2 bw = __half22float2(wh[s]);
        acc += a.x * wbase[olo] + bw.x * wbase[olo + 1];
        acc += a.y * wbase[ohi] + bw.y * wbase[ohi + 1];
    }

    if (lane < NBIN) {
        __builtin_nontemporal_store(
            acc, out + (size_t)m * COUT + (size_t)c * NBIN + lane);
    }
}

extern "C" void kernel_launch(void* const* d_in, const int* in_sizes, int n_in,
                              void* d_out, int out_size, void* d_ws, size_t ws_size,
                              hipStream_t stream) {
    const float* f2    = (const float*)d_in[0];
    const float* f3    = (const float*)d_in[1];
    const float* f4    = (const float*)d_in[2];
    const float* f5    = (const float*)d_in[3];
    const float* boxes = (const float*)d_in[4];
    float* outp = (float*)d_out;

    int*      hdr  = (int*)d_ws;                         // 1024*8*4  = 32 KB
    uint32_t* taps = (uint32_t*)d_ws + NBOX * HDRN;      // 1024*588*4 ≈ 2.4 MB

    box_prep_kernel<<<dim3(NBOX), dim3(64), 0, stream>>>(boxes, hdr, taps);
    roi_align_kernel<<<dim3(NBOX * BPB), dim3(256), 0, stream>>>(
        f2, f3, f4, f5, hdr, taps, outp);
}

// Round 13
// 110.328 us; speedup vs baseline: 1.4785x; 1.4785x over previous
//
#include <hip/hip_runtime.h>
#include <hip/hip_fp16.h>
#include <math.h>
#include <stdint.h>

#define NBATCH 2
#define KBOX   512
#define NBOX   (NBATCH*KBOX)
#define CCH    256
#define NBIN   49                 // 7x7 bins
#define NCH    4                  // channels per block = waves per block
#define BPB    (CCH/NCH)          // 64 blocks per box
#define COUT   (CCH*NBIN)         // 12544 outputs per box
#define WCAP   1280               // floats per channel window; proven max 1120 (+sentinel)
#define HDRN   32                 // ints per box header (8 scalars + 14 packed row words)
#define TAPN   (12*NBIN)          // 588 packed dwords per box

typedef const uint32_t __attribute__((address_space(1)))* gas_u32p;
typedef uint32_t       __attribute__((address_space(3)))* las_u32p;

// ---- kernel 1: single-source FP; bitmap-rank row compaction (correct by construction) ----
__global__ __launch_bounds__(64) void box_prep_kernel(
    const float* __restrict__ boxes, int* __restrict__ hdr, uint32_t* __restrict__ taps)
{
    const int m    = blockIdx.x;
    const int lane = threadIdx.x;

    __shared__ float    s_fy[14], s_fx[14];
    __shared__ int      s_slo[14], s_shi[14], s_xr[14];
    __shared__ int      s_vy[14], s_vx[14];
    __shared__ int      s_wsp4;
    __shared__ uint16_t s_roff[28];

    const float x1 = boxes[m*4+0];
    const float y1 = boxes[m*4+1];
    const float x2 = boxes[m*4+2];
    const float y2 = boxes[m*4+3];

    const float area = (x2 - x1) * (y2 - y1);
    const float size = sqrtf(area);
    float lvlf = floorf(4.0f + log2f(size / 224.0f + 1e-8f));
    lvlf = fminf(fmaxf(lvlf, 2.0f), 5.0f);
    const int lvl = (int)lvlf - 2;    // 0..3

    const int   H     = 256 >> lvl;
    const float scale = 0.25f / (float)(1 << lvl);
    const float Hf    = (float)H;

    const float bx1 = x1 * scale - 0.5f;
    const float by1 = y1 * scale - 0.5f;
    const float bin_w = (x2 * scale - 0.5f - bx1) / 7.0f;
    const float bin_h = (y2 * scale - 0.5f - by1) / 7.0f;

    if (lane == 0) {
        // ---- x pass: 14 samples, each floor computed exactly once ----
        int xls[14];
        #pragma unroll 1
        for (int i = 0; i < 14; ++i) {
            const float gx = ((float)i + 0.5f) * 0.5f;
            const float xx = bx1 + gx * bin_w;
            s_vx[i] = (xx >= -1.0f) && (xx <= Hf);
            const float xc = fmaxf(xx, 0.0f);
            const int xl = min((int)floorf(xc), H - 1);
            const int xh = min(xl + 1, H - 1);
            float fx = xc - (float)xl;
            if (xh == xl) fx = 0.0f;            // clamped pair: hi weight 0 (exact)
            s_fx[i] = fx;
            xls[i] = xl;
        }
        const int wx0a = xls[0] & ~3;                      // xls monotone -> min is xls[0]
        const int xh13 = min(xls[13] + 1, H - 1);          // max column touched
        const int wsp4 = ((xh13 - wx0a + 1 + 3) >> 2) << 2;
        s_wsp4 = wsp4;
        #pragma unroll 1
        for (int i = 0; i < 14; ++i) s_xr[i] = xls[i] - wx0a;

        // ---- y pass: floors once; 256-bit row bitmap ----
        unsigned long long bm[4] = {0ull, 0ull, 0ull, 0ull};
        int yls[14], yhs[14];
        #pragma unroll 1
        for (int j = 0; j < 14; ++j) {
            const float gy = ((float)j + 0.5f) * 0.5f;
            const float yy = by1 + gy * bin_h;
            s_vy[j] = (yy >= -1.0f) && (yy <= Hf);
            const float yc = fmaxf(yy, 0.0f);
            const int yl = min((int)floorf(yc), H - 1);
            const int yh = min(yl + 1, H - 1);
            s_fy[j] = yc - (float)yl;
            yls[j] = yl; yhs[j] = yh;
            bm[yl >> 6] |= 1ull << (yl & 63);
            bm[yh >> 6] |= 1ull << (yh & 63);
        }
        // rank = popcount below; list = set bits ascending (definitionally consistent)
        int cum[4];
        cum[0] = 0;
        cum[1] = cum[0] + (int)__popcll(bm[0]);
        cum[2] = cum[1] + (int)__popcll(bm[1]);
        cum[3] = cum[2] + (int)__popcll(bm[2]);
        const int nr = cum[3] + (int)__popcll(bm[3]);
        #pragma unroll 1
        for (int j = 0; j < 14; ++j) {
            const int yl = yls[j], yh = yhs[j];
            s_slo[j] = cum[yl >> 6] + (int)__popcll(bm[yl >> 6] & ((1ull << (yl & 63)) - 1ull));
            s_shi[j] = cum[yh >> 6] + (int)__popcll(bm[yh >> 6] & ((1ull << (yh & 63)) - 1ull));
        }
        int slot = 0;
        #pragma unroll 1
        for (int w = 0; w < 4; ++w) {
            unsigned long long t = bm[w];
            while (t) {
                const int b = __builtin_ctzll(t);
                t &= t - 1ull;
                s_roff[slot++] = (uint16_t)(((w << 6) + b) * H + wx0a);
            }
        }
        #pragma unroll 1
        for (int r = slot; r < 28; ++r) s_roff[r] = s_roff[slot - 1];

        // ---- header ----
        int* h = hdr + m * HDRN;
        const int qpr = wsp4 >> 2;
        const int nq  = nr * qpr;               // quads per channel window (<=280)
        h[0] = lvl;
        h[1] = H;
        h[2] = H * H;
        h[3] = qpr;
        h[4] = nq;
        h[5] = __float_as_int(1.0f / (float)qpr);
        h[6] = nq << 2;                         // sentinel float index
        h[7] = 0;
        uint32_t* hw = (uint32_t*)(h + 8);
        #pragma unroll 1
        for (int k = 0; k < 14; ++k)
            hw[k] = (uint32_t)s_roff[2*k] | ((uint32_t)s_roff[2*k+1] << 16);
    }
    __syncthreads();

    // ---- tap build: pure combination of shared values (no duplicated FP) ----
    if (lane < NBIN) {
        const int py = lane / 7;
        const int px = lane - py * 7;
        const uint32_t base = (uint32_t)m * TAPN;
        __half2* th = (__half2*)taps;
        const int wsp4 = s_wsp4;

        #pragma unroll
        for (int s = 0; s < 4; ++s) {
            const int j = 2*py + (s >> 1);
            const int i = 2*px + (s & 1);
            const float fy = s_fy[j];
            const float fx = s_fx[i];
            const float vm = (s_vy[j] && s_vx[i]) ? 0.25f : 0.0f;
            const float wyl = (1.0f - fy) * vm;
            const float wyh = fy * vm;

            const uint32_t olo = (uint32_t)(s_slo[j] * wsp4 + s_xr[i]);
            const uint32_t ohi = (uint32_t)(s_shi[j] * wsp4 + s_xr[i]);

            taps[base + s*NBIN + lane] = olo | (ohi << 16);
            th  [base + (4+s)*NBIN + lane] = __floats2half2_rn(wyl*(1.0f-fx), wyh*(1.0f-fx));
            th  [base + (8+s)*NBIN + lane] = __floats2half2_rn(wyl*fx,        wyh*fx);
        }
    }
}

// -------- kernel 2: per-wave channel; CONVERGED staging loop (shfl needs all lanes) --------
__global__ __launch_bounds__(256, 8) void roi_align_kernel(
    const float* __restrict__ f2, const float* __restrict__ f3,
    const float* __restrict__ f4, const float* __restrict__ f5,
    const int* __restrict__ hdr, const uint32_t* __restrict__ taps,
    float* __restrict__ out)
{
    const int bid  = blockIdx.x;
    const int m    = bid >> 6;        // consecutive blocks -> same box (L3 locality)
    const int cg   = bid & 63;
    const int tid  = threadIdx.x;
    const int lane = tid & 63;
    const int wid  = tid >> 6;
    const int b    = m >> 9;          // batch (KBOX == 512)

    __shared__ float win[NCH * WCAP];

    const int* h = hdr + m * HDRN;
    const int   lvl = h[0];
    const int   HH  = h[2];
    const int   qpr = h[3];
    const int   nq  = h[4];
    const float rq  = __int_as_float(h[5]);
    const int   nq4 = h[6];

    // packed row offsets: lane l holds word min(l,13); fan out via shfl
    const uint32_t roww = ((const uint32_t*)(h + 8))[min(lane, 13)];

    const float* fptr = (lvl == 0) ? f2 : (lvl == 1) ? f3 : (lvl == 2) ? f4 : f5;
    const int c = cg * NCH + wid;     // this wave's channel
    const float* plane = fptr + ((size_t)(b * CCH + c)) * HH;
    float* wbase = win + wid * WCAP;  // this wave's private LDS segment

    // ---- stage compacted rows: 16B quads, HBM -> LDS direct ----
    // Uniform trip count; __shfl executed with ALL lanes active (ds_bpermute from
    // an exec-masked lane is undefined -- this was the r10-r12 bug). Only the
    // load itself is predicated.
    const int niter = (nq + 63) >> 6;
    for (int it = 0; it < niter; ++it) {
        const int iq  = (it << 6) + lane;
        const int iqc = min(iq, nq - 1);                   // clamp for address math
        const int slot = (int)(((float)iqc + 0.5f) * rq);  // iqc/qpr, exact (margin 0.5/qpr)
        const int cq   = iqc - slot * qpr;
        const uint32_t w2 = (uint32_t)__shfl((int)roww, slot >> 1, 64);
        const int roff = (slot & 1) ? (int)(w2 >> 16) : (int)(w2 & 0xffffu);
        if (iq < nq) {
            __builtin_amdgcn_global_load_lds(
                (gas_u32p)(const void*)(plane + roff + (cq << 2)),
                (las_u32p)(void*)(&wbase[it << 8]),        // uniform base + lane*16B
                16, 0, 0);
        }
    }
    // sentinel: the one-past-end slot a clamped x-hi pair read touches (weight 0)
    if (lane == 0) wbase[nq4] = 0.0f;

    // ---- packed taps: 12 coalesced dword loads (overlap staging) ----
    const int l = (lane < NBIN) ? lane : NBIN - 1;
    const uint32_t* tb = taps + (uint32_t)m * TAPN;
    const __half2*  th = (const __half2*)tb;

    uint32_t po[4];
    __half2  wl[4], wh[4];
    #pragma unroll
    for (int s = 0; s < 4; ++s) po[s] = tb[s*NBIN + l];
    #pragma unroll
    for (int s = 0; s < 4; ++s) wl[s] = th[(4+s)*NBIN + l];
    #pragma unroll
    for (int s = 0; s < 4; ++s) wh[s] = th[(8+s)*NBIN + l];

    // wave-local drain; fence the scheduler (rule #18)
    asm volatile("s_waitcnt vmcnt(0) lgkmcnt(0)" ::: "memory");
    __builtin_amdgcn_sched_barrier(0);

    // ---- compute: 16 LDS reads + 16 FMAs + 1 store ----
    float acc = 0.0f;
    #pragma unroll
    for (int s = 0; s < 4; ++s) {
        const int olo = (int)(po[s] & 0xffffu);
        const int ohi = (int)(po[s] >> 16);
        const float2 a  = __half22float2(wl[s]);
        const float2 bw = __half22float2(wh[s]);
        acc += a.x * wbase[olo] + bw.x * wbase[olo + 1];
        acc += a.y * wbase[ohi] + bw.y * wbase[ohi + 1];
    }

    if (lane < NBIN) {
        __builtin_nontemporal_store(
            acc, out + (size_t)m * COUT + (size_t)c * NBIN + lane);
    }
}

extern "C" void kernel_launch(void* const* d_in, const int* in_sizes, int n_in,
                              void* d_out, int out_size, void* d_ws, size_t ws_size,
                              hipStream_t stream) {
    const float* f2    = (const float*)d_in[0];
    const float* f3    = (const float*)d_in[1];
    const float* f4    = (const float*)d_in[2];
    const float* f5    = (const float*)d_in[3];
    const float* boxes = (const float*)d_in[4];
    float* outp = (float*)d_out;

    int*      hdr  = (int*)d_ws;                         // 1024*32*4 = 128 KB
    uint32_t* taps = (uint32_t*)d_ws + NBOX * HDRN;      // 1024*588*4 ≈ 2.4 MB

    box_prep_kernel<<<dim3(NBOX), dim3(64), 0, stream>>>(boxes, hdr, taps);
    roi_align_kernel<<<dim3(NBOX * BPB), dim3(256), 0, stream>>>(
        f2, f3, f4, f5, hdr, taps, outp);
}